// Round 16
// baseline (260.909 us; speedup 1.0000x reference)
//
#include <hip/hip_runtime.h>

using f32x4 = __attribute__((ext_vector_type(4))) float;
using s16x8 = __attribute__((ext_vector_type(8))) short;
using u16x4 = __attribute__((ext_vector_type(4))) unsigned short;
using u32 = unsigned int;

static __device__ __forceinline__ unsigned short f2bf(float f) {
  u32 u = __builtin_bit_cast(u32, f);
  u = (u + 0x7fffu + ((u >> 16) & 1u)) >> 16;
  return (unsigned short)u;
}

static __device__ __forceinline__ void gload_lds16(const void* g, void* l) {
  __builtin_amdgcn_global_load_lds((const __attribute__((address_space(1))) void*)g,
                                   (__attribute__((address_space(3))) void*)l, 16, 0, 0);
}

// ---------------- fused fp32 -> bf16 conversion (all 6 tensors, one launch) ----------------
__global__ void k_cvt_all(const float* __restrict__ x, const float* __restrict__ Wqd,
                          const float* __restrict__ Wkd, const float* __restrict__ Wvd,
                          const float* __restrict__ Wvu, const float* __restrict__ Wo,
                          unsigned short* __restrict__ xb, unsigned short* __restrict__ Wdb,
                          unsigned short* __restrict__ Wvub, unsigned short* __restrict__ Wob) {
  int i = blockIdx.x * blockDim.x + threadIdx.x;  // float4 index, total 1572864
  const float* s;
  unsigned short* d;
  int off;
  if (i < 1048576) { s = x; d = xb; off = i; }
  else if (i < 1114112) { s = Wqd; d = Wdb; off = i - 1048576; }
  else if (i < 1179648) { s = Wkd; d = Wdb + 262144; off = i - 1114112; }
  else if (i < 1245184) { s = Wvd; d = Wdb + 524288; off = i - 1179648; }
  else if (i < 1310720) { s = Wvu; d = Wvub; off = i - 1245184; }
  else { s = Wo; d = Wob; off = i - 1310720; }
  float4 v = reinterpret_cast<const float4*>(s)[off];
  u16x4 o;
  o[0] = f2bf(v.x); o[1] = f2bf(v.y); o[2] = f2bf(v.z); o[3] = f2bf(v.w);
  reinterpret_cast<u16x4*>(d)[off] = o;
}

// ---------------- MabsT[h][k][q] = 0.125 * sum_d Wq_up[h*64+d][q] * Wk_up[h*64+d][k] ----------------
__global__ void k_mabs(const float* __restrict__ Wqu, const float* __restrict__ Wku,
                       unsigned short* __restrict__ MabsT) {
  __shared__ float sq[64][65];
  __shared__ float sk[64][65];
  int h = blockIdx.z, q0 = blockIdx.x * 64, k0 = blockIdx.y * 64;
  int t = threadIdx.x;
  for (int r = 0; r < 16; ++r) {
    int d = r * 4 + (t >> 6);
    int c = t & 63;
    sq[d][c] = Wqu[(size_t)(h * 64 + d) * 256 + q0 + c];
    sk[d][c] = Wku[(size_t)(h * 64 + d) * 256 + k0 + c];
  }
  __syncthreads();
  int kk = t >> 2, qs = t & 3;
  float acc[16];
#pragma unroll
  for (int j = 0; j < 16; ++j) acc[j] = 0.f;
  for (int d = 0; d < 64; ++d) {
    float kv = sk[d][kk];
#pragma unroll
    for (int j = 0; j < 16; ++j) acc[j] += kv * sq[d][qs + 4 * j];
  }
#pragma unroll
  for (int j = 0; j < 16; ++j)
    MabsT[((size_t)(h * 256 + k0 + kk)) * 256 + q0 + qs + 4 * j] = f2bf(acc[j] * 0.125f);
}

// ---------------- NT-GEMM, gload_lds double-buffered, templated on BN,BK ----------------
// BM=128 fixed. 4 waves: wr=w>>1 over 64 rows, wc=w&1 over BN/2 cols.
// modes: 0 = bf16 C row-major; 1 = fp32 C row-major + bias; 2 = bf16 Qabs scatter
template <int BN, int BK>
__global__ __launch_bounds__(256) void k_gemm(
    const unsigned short* __restrict__ A, int lda,
    const unsigned short* __restrict__ B0, int ldb, long bstride,
    void* __restrict__ C, const float* __restrict__ bias,
    int M, int N, int K, int ldc, int mode) {
  constexpr int NR = BN / 32;       // fragments per wave in N
  constexpr int KR = BK / 32;       // k-subtiles per LDS tile
  constexpr int RA = BK / 16;       // A staging rounds (128*BK*2 / 4096)
  constexpr int RB = BN * BK / 2048;  // B staging rounds
  __shared__ unsigned short As[2][128 * BK];
  __shared__ unsigned short Bs[2][BN * BK];
  int bz = blockIdx.z;
  const unsigned short* B = B0 + (size_t)bz * bstride;
  int row0 = blockIdx.x * 128, col0 = blockIdx.y * BN;
  int t = threadIdx.x;
  int lane = t & 63, w = t >> 6;
  int wr = w >> 1, wc = w & 1;
  int lc = lane & 15, kr = (lane >> 4) * 8;

#define STAGE(bufi, k0g)                                                                   \
  {                                                                                        \
    _Pragma("unroll") for (int c = 0; c < RA; ++c) {                                       \
      int f = (c * 256 + t) * 16;                                                          \
      int r = f / (2 * BK), kb = (f % (2 * BK)) >> 1;                                      \
      gload_lds16(A + (size_t)(row0 + r) * lda + (k0g) + kb,                               \
                  (char*)&As[bufi][0] + c * 4096 + w * 1024);                              \
    }                                                                                      \
    _Pragma("unroll") for (int c = 0; c < RB; ++c) {                                       \
      int f = (c * 256 + t) * 16;                                                          \
      int r = f / (2 * BK), kb = (f % (2 * BK)) >> 1;                                      \
      gload_lds16(B + (size_t)(col0 + r) * ldb + (k0g) + kb,                               \
                  (char*)&Bs[bufi][0] + c * 4096 + w * 1024);                              \
    }                                                                                      \
  }

  f32x4 acc[4][NR];
#pragma unroll
  for (int m = 0; m < 4; ++m)
#pragma unroll
    for (int n = 0; n < NR; ++n) acc[m][n] = (f32x4){0.f, 0.f, 0.f, 0.f};

  STAGE(0, 0)
  asm volatile("s_waitcnt vmcnt(0)" ::: "memory");
  __syncthreads();

  int cur = 0;
  for (int k0 = 0; k0 < K; k0 += BK) {
    const bool pfn = (k0 + BK < K);
    if (pfn) { STAGE(cur ^ 1, k0 + BK) }

    s16x8 af[KR][4], bf[KR][NR];
#pragma unroll
    for (int k2 = 0; k2 < KR; ++k2) {
#pragma unroll
      for (int m = 0; m < 4; ++m)
        af[k2][m] = *(const s16x8*)&As[cur][(wr * 64 + m * 16 + lc) * BK + k2 * 32 + kr];
#pragma unroll
      for (int n = 0; n < NR; ++n)
        bf[k2][n] = *(const s16x8*)&Bs[cur][(wc * (BN / 2) + n * 16 + lc) * BK + k2 * 32 + kr];
    }
#pragma unroll
    for (int k2 = 0; k2 < KR; ++k2)
#pragma unroll
      for (int m = 0; m < 4; ++m)
#pragma unroll
        for (int n = 0; n < NR; ++n)
          acc[m][n] = __builtin_amdgcn_mfma_f32_16x16x32_bf16(af[k2][m], bf[k2][n],
                                                              acc[m][n], 0, 0, 0);

    asm volatile("s_waitcnt vmcnt(0)" ::: "memory");
    __syncthreads();
    cur ^= 1;
  }

  int rbase = row0 + wr * 64, cbase = col0 + wc * (BN / 2);
  int lr4 = (lane >> 4) * 4;
#pragma unroll
  for (int m = 0; m < 4; ++m)
#pragma unroll
    for (int n = 0; n < NR; ++n)
#pragma unroll
      for (int r = 0; r < 4; ++r) {
        int grow = rbase + m * 16 + lr4 + r;
        int gcol = cbase + n * 16 + lc;
        float v = acc[m][n][r];
        if (mode == 0) {
          ((unsigned short*)C)[(size_t)grow * ldc + gcol] = f2bf(v);
        } else if (mode == 1) {
          ((float*)C)[(size_t)grow * ldc + gcol] = v + bias[gcol];
        } else {
          int b_ = grow >> 11, t_ = grow & 2047;
          ((unsigned short*)C)[(((size_t)(b_ * 16 + bz)) * 2048 + t_) * 256 + gcol] = f2bf(v);
        }
      }
#undef STAGE
}

// ---------------- flash attention: R13-exact (paired tiles, 2 blocks/CU, LDS V, setprio) ----------------
__global__ __launch_bounds__(256, 2) void k_attn(
    const unsigned short* __restrict__ Qabs, const unsigned short* __restrict__ Lat,
    const unsigned short* __restrict__ VupT, unsigned short* __restrict__ ctx) {
  __shared__ unsigned short Ks[2][32 * 264];
  __shared__ unsigned short Vs[2][64 * 40];
  __shared__ unsigned short Pl[4][16 * 40];

  const int bx = blockIdx.x;
  const int bh = blockIdx.y;
  const int b = bh >> 4, h = bh & 15;
  const int t = threadIdx.x, lane = t & 63, w = t >> 6;
  const int lrow = lane & 15, hi = lane >> 4;
  const int kr = hi * 8;

  const unsigned short* Q = Qabs + (size_t)bh * 2048 * 256;
  const unsigned short* Kp = Lat + (size_t)b * 2048 * 768 + 256;
  const unsigned short* Vp = VupT + (size_t)(h * 64) * 4096 + b * 2048;
  unsigned short* Op = ctx + (size_t)b * 2048 * 1024 + h * 64;

  uint4 kstg[4];
  uint4 vstg;
  const int krr0 = t >> 5;
  const int kcc = t & 31;
  const int vrr = t >> 2, vcc = t & 3;

#define K_ISSUE(s0g)                                                           \
  {                                                                            \
    _Pragma("unroll") for (int c = 0; c < 4; ++c) kstg[c] =                    \
        *(const uint4*)(Kp + (size_t)((s0g) + c * 8 + krr0) * 768 + kcc * 8);  \
    vstg = *(const uint4*)(Vp + (size_t)vrr * 4096 + (s0g) + vcc * 8);         \
  }
#define KV_WRITE(bufi)                                                         \
  {                                                                            \
    _Pragma("unroll") for (int c = 0; c < 4; ++c)                              \
        *(uint4*)&Ks[bufi][(c * 8 + krr0) * 264 + kcc * 8] = kstg[c];          \
    *(uint4*)&Vs[bufi][vrr * 40 + vcc * 8] = vstg;                             \
  }

  for (int seg = 0; seg < 2; ++seg) {
    const int tb = (seg == 0 ? bx : 31 - bx) * 64;
    const int qb = tb + w * 16;

    s16x8 qf[8];
#pragma unroll
    for (int kk = 0; kk < 8; ++kk)
      qf[kk] = *(const s16x8*)&Q[(size_t)(qb + lrow) * 256 + kk * 32 + kr];

    f32x4 o[4];
#pragma unroll
    for (int dt = 0; dt < 4; ++dt) o[dt] = (f32x4){0.f, 0.f, 0.f, 0.f};
    float mrow[4], lsum[4];
    int myrow[4];
#pragma unroll
    for (int r = 0; r < 4; ++r) {
      mrow[r] = -1e30f;
      lsum[r] = 0.f;
      myrow[r] = qb + hi * 4 + r;
    }

    K_ISSUE(0)
    KV_WRITE(0)
    __syncthreads();

    const int nsteps = tb / 32 + 2;
    for (int st = 0; st < nsteps; ++st) {
      const int buf = st & 1;
      const int s0 = st * 32;
      const bool pfn = (st + 1 < nsteps);
      if (pfn) { K_ISSUE(s0 + 32) }

      s16x8 kfa[2][8];
#pragma unroll
      for (int hf = 0; hf < 2; ++hf)
#pragma unroll
        for (int kk = 0; kk < 8; ++kk)
          kfa[hf][kk] = *(const s16x8*)&Ks[buf][(hf * 16 + lrow) * 264 + kk * 32 + kr];

      f32x4 sf[2];
      sf[0] = (f32x4){0.f, 0.f, 0.f, 0.f};
      sf[1] = (f32x4){0.f, 0.f, 0.f, 0.f};
      __builtin_amdgcn_s_setprio(1);
#pragma unroll
      for (int kk = 0; kk < 8; ++kk) {
        sf[0] = __builtin_amdgcn_mfma_f32_16x16x32_bf16(qf[kk], kfa[0][kk], sf[0], 0, 0, 0);
        sf[1] = __builtin_amdgcn_mfma_f32_16x16x32_bf16(qf[kk], kfa[1][kk], sf[1], 0, 0, 0);
      }
      __builtin_amdgcn_s_setprio(0);

#pragma unroll
      for (int r = 0; r < 4; ++r) {
        int q = myrow[r];
        if (s0 + lrow > q) sf[0][r] = -1e30f;
        if (s0 + 16 + lrow > q) sf[1][r] = -1e30f;
        float mloc = fmaxf(sf[0][r], sf[1][r]);
        if (!__all(mloc <= mrow[r] + 8.f)) {
          float mx = mloc;
#pragma unroll
          for (int off = 1; off < 16; off <<= 1) mx = fmaxf(mx, __shfl_xor(mx, off));
          float mnew = fmaxf(mrow[r], mx);
          float scale = __expf(mrow[r] - mnew);
          mrow[r] = mnew;
          lsum[r] *= scale;
#pragma unroll
          for (int dt = 0; dt < 4; ++dt) o[dt][r] *= scale;
        }
        float p0 = __expf(sf[0][r] - mrow[r]);
        float p1 = __expf(sf[1][r] - mrow[r]);
        sf[0][r] = p0;
        sf[1][r] = p1;
        lsum[r] += p0 + p1;
      }
#pragma unroll
      for (int r = 0; r < 4; ++r) {
        Pl[w][(hi * 4 + r) * 40 + lrow] = f2bf(sf[0][r]);
        Pl[w][(hi * 4 + r) * 40 + 16 + lrow] = f2bf(sf[1][r]);
      }
      asm volatile("s_waitcnt lgkmcnt(0)" ::: "memory");
      __builtin_amdgcn_sched_barrier(0);

      s16x8 pf = *(const s16x8*)&Pl[w][lrow * 40 + kr];
      s16x8 vfa[4];
#pragma unroll
      for (int dt = 0; dt < 4; ++dt)
        vfa[dt] = *(const s16x8*)&Vs[buf][(dt * 16 + lrow) * 40 + kr];
      __builtin_amdgcn_s_setprio(1);
#pragma unroll
      for (int dt = 0; dt < 4; ++dt)
        o[dt] = __builtin_amdgcn_mfma_f32_16x16x32_bf16(pf, vfa[dt], o[dt], 0, 0, 0);
      __builtin_amdgcn_s_setprio(0);

      if (pfn) { KV_WRITE(buf ^ 1) }
      __syncthreads();
    }

#pragma unroll
    for (int r = 0; r < 4; ++r) {
      float ls = lsum[r];
#pragma unroll
      for (int off = 1; off < 16; off <<= 1) ls += __shfl_xor(ls, off);
      lsum[r] = ls;
    }
#pragma unroll
    for (int dt = 0; dt < 4; ++dt)
#pragma unroll
      for (int r = 0; r < 4; ++r) {
        float v = o[dt][r] / lsum[r];
        Op[(size_t)myrow[r] * 1024 + dt * 16 + lrow] = f2bf(v);
      }
    __syncthreads();
  }
#undef K_ISSUE
#undef KV_WRITE
}

extern "C" void kernel_launch(void* const* d_in, const int* in_sizes, int n_in,
                              void* d_out, int out_size, void* d_ws, size_t ws_size,
                              hipStream_t stream) {
  const float* x = (const float*)d_in[0];
  const float* Wqd = (const float*)d_in[2];
  const float* Wkd = (const float*)d_in[3];
  const float* Wvd = (const float*)d_in[4];
  const float* Wqu = (const float*)d_in[5];
  const float* Wku = (const float*)d_in[6];
  const float* Wvu = (const float*)d_in[7];
  const float* Wo = (const float*)d_in[8];
  const float* bo = (const float*)d_in[9];
  float* out = (float*)d_out;

  char* ws = (char*)d_ws;
  unsigned short* xb = (unsigned short*)(ws);                // 4096x1024 bf16
  unsigned short* Wdb = (unsigned short*)(ws + 8388608);     // 768x1024
  unsigned short* Wvub = (unsigned short*)(ws + 9961472);    // 1024x256
  unsigned short* Wob = (unsigned short*)(ws + 10485760);    // 1024x1024
  unsigned short* MabsT = (unsigned short*)(ws + 12582912);  // 16x256x256
  unsigned short* Lat = (unsigned short*)(ws + 14680064);    // 4096x768 (Q|K|V latents)
  unsigned short* Qabs = (unsigned short*)(ws + 20971520);   // 32x2048x256
  unsigned short* VupT = (unsigned short*)(ws + 54525952);   // [1024][4096] d-major
  unsigned short* ctx = (unsigned short*)(ws + 62914560);    // 4096x1024

  k_cvt_all<<<6144, 256, 0, stream>>>(x, Wqd, Wkd, Wvd, Wvu, Wo, xb, Wdb, Wvub, Wob);
  k_mabs<<<dim3(4, 4, 16), 256, 0, stream>>>(Wqu, Wku, MabsT);
  // latents: [4096,768] = xb @ Wdb^T   (BN=64, BK=64 -> 16 K-steps)
  k_gemm<64, 64><<<dim3(32, 12, 1), 256, 0, stream>>>(xb, 1024, Wdb, 1024, 0, Lat, nullptr,
                                                      4096, 768, 1024, 768, 0);
  // Qabs per head (mode 2 scatter): proven BN=128, BK=32 config
  k_gemm<128, 32><<<dim3(32, 2, 16), 256, 0, stream>>>(Lat, 768, MabsT, 256, 65536, Qabs,
                                                       nullptr, 4096, 256, 256, 0, 2);
  // VupT [1024][4096] = Wvub @ V_lat^T  (BN=64, BK=64 -> 4 K-steps)
  k_gemm<64, 64><<<dim3(8, 64, 1), 256, 0, stream>>>(Wvub, 256, Lat + 512, 768, 0, VupT,
                                                     nullptr, 1024, 4096, 256, 4096, 0);
  k_attn<<<dim3(16, 32), 256, 0, stream>>>(Qabs, Lat, VupT, ctx);
  // out = ctx @ Wo^T + bo (fp32, BN=64, BK=64 -> 16 K-steps)
  k_gemm<64, 64><<<dim3(32, 16, 1), 256, 0, stream>>>(ctx, 1024, Wob, 1024, 0, out, bo,
                                                      4096, 1024, 1024, 1024, 1);
}

// Round 17
// 258.707 us; speedup vs baseline: 1.0085x; 1.0085x over previous
//
#include <hip/hip_runtime.h>

using f32x4 = __attribute__((ext_vector_type(4))) float;
using s16x8 = __attribute__((ext_vector_type(8))) short;
using u16x4 = __attribute__((ext_vector_type(4))) unsigned short;
using u32 = unsigned int;

static __device__ __forceinline__ unsigned short f2bf(float f) {
  u32 u = __builtin_bit_cast(u32, f);
  u = (u + 0x7fffu + ((u >> 16) & 1u)) >> 16;
  return (unsigned short)u;
}

static __device__ __forceinline__ void gload_lds16(const void* g, void* l) {
  __builtin_amdgcn_global_load_lds((const __attribute__((address_space(1))) void*)g,
                                   (__attribute__((address_space(3))) void*)l, 16, 0, 0);
}

// ---------------- fused fp32 -> bf16 conversion (all 6 tensors, one launch) ----------------
__global__ void k_cvt_all(const float* __restrict__ x, const float* __restrict__ Wqd,
                          const float* __restrict__ Wkd, const float* __restrict__ Wvd,
                          const float* __restrict__ Wvu, const float* __restrict__ Wo,
                          unsigned short* __restrict__ xb, unsigned short* __restrict__ Wdb,
                          unsigned short* __restrict__ Wvub, unsigned short* __restrict__ Wob) {
  int i = blockIdx.x * blockDim.x + threadIdx.x;  // float4 index, total 1572864
  const float* s;
  unsigned short* d;
  int off;
  if (i < 1048576) { s = x; d = xb; off = i; }
  else if (i < 1114112) { s = Wqd; d = Wdb; off = i - 1048576; }
  else if (i < 1179648) { s = Wkd; d = Wdb + 262144; off = i - 1114112; }
  else if (i < 1245184) { s = Wvd; d = Wdb + 524288; off = i - 1179648; }
  else if (i < 1310720) { s = Wvu; d = Wvub; off = i - 1245184; }
  else { s = Wo; d = Wob; off = i - 1310720; }
  float4 v = reinterpret_cast<const float4*>(s)[off];
  u16x4 o;
  o[0] = f2bf(v.x); o[1] = f2bf(v.y); o[2] = f2bf(v.z); o[3] = f2bf(v.w);
  reinterpret_cast<u16x4*>(d)[off] = o;
}

// ---------------- MabsT[h][k][q] = 0.125 * sum_d Wq_up[h*64+d][q] * Wk_up[h*64+d][k] ----------------
__global__ void k_mabs(const float* __restrict__ Wqu, const float* __restrict__ Wku,
                       unsigned short* __restrict__ MabsT) {
  __shared__ float sq[64][65];
  __shared__ float sk[64][65];
  int h = blockIdx.z, q0 = blockIdx.x * 64, k0 = blockIdx.y * 64;
  int t = threadIdx.x;
  for (int r = 0; r < 16; ++r) {
    int d = r * 4 + (t >> 6);
    int c = t & 63;
    sq[d][c] = Wqu[(size_t)(h * 64 + d) * 256 + q0 + c];
    sk[d][c] = Wku[(size_t)(h * 64 + d) * 256 + k0 + c];
  }
  __syncthreads();
  int kk = t >> 2, qs = t & 3;
  float acc[16];
#pragma unroll
  for (int j = 0; j < 16; ++j) acc[j] = 0.f;
  for (int d = 0; d < 64; ++d) {
    float kv = sk[d][kk];
#pragma unroll
    for (int j = 0; j < 16; ++j) acc[j] += kv * sq[d][qs + 4 * j];
  }
#pragma unroll
  for (int j = 0; j < 16; ++j)
    MabsT[((size_t)(h * 256 + k0 + kk)) * 256 + q0 + qs + 4 * j] = f2bf(acc[j] * 0.125f);
}

// ---------------- NT-GEMM, gload_lds double-buffered, templated on BN,BK ----------------
// BM=128 fixed. 4 waves: wr=w>>1 over 64 rows, wc=w&1 over BN/2 cols.
// modes: 0 = bf16 C row-major; 1 = fp32 C row-major + bias; 2 = bf16 Qabs scatter
template <int BN, int BK>
__global__ __launch_bounds__(256) void k_gemm(
    const unsigned short* __restrict__ A, int lda,
    const unsigned short* __restrict__ B0, int ldb, long bstride,
    void* __restrict__ C, const float* __restrict__ bias,
    int M, int N, int K, int ldc, int mode) {
  constexpr int NR = BN / 32;       // fragments per wave in N
  constexpr int KR = BK / 32;       // k-subtiles per LDS tile
  constexpr int RA = BK / 16;       // A staging rounds (128*BK*2 / 4096)
  constexpr int RB = BN * BK / 2048;  // B staging rounds
  __shared__ unsigned short As[2][128 * BK];
  __shared__ unsigned short Bs[2][BN * BK];
  int bz = blockIdx.z;
  const unsigned short* B = B0 + (size_t)bz * bstride;
  int row0 = blockIdx.x * 128, col0 = blockIdx.y * BN;
  int t = threadIdx.x;
  int lane = t & 63, w = t >> 6;
  int wr = w >> 1, wc = w & 1;
  int lc = lane & 15, kr = (lane >> 4) * 8;

#define STAGE(bufi, k0g)                                                                   \
  {                                                                                        \
    _Pragma("unroll") for (int c = 0; c < RA; ++c) {                                       \
      int f = (c * 256 + t) * 16;                                                          \
      int r = f / (2 * BK), kb = (f % (2 * BK)) >> 1;                                      \
      gload_lds16(A + (size_t)(row0 + r) * lda + (k0g) + kb,                               \
                  (char*)&As[bufi][0] + c * 4096 + w * 1024);                              \
    }                                                                                      \
    _Pragma("unroll") for (int c = 0; c < RB; ++c) {                                       \
      int f = (c * 256 + t) * 16;                                                          \
      int r = f / (2 * BK), kb = (f % (2 * BK)) >> 1;                                      \
      gload_lds16(B + (size_t)(col0 + r) * ldb + (k0g) + kb,                               \
                  (char*)&Bs[bufi][0] + c * 4096 + w * 1024);                              \
    }                                                                                      \
  }

  f32x4 acc[4][NR];
#pragma unroll
  for (int m = 0; m < 4; ++m)
#pragma unroll
    for (int n = 0; n < NR; ++n) acc[m][n] = (f32x4){0.f, 0.f, 0.f, 0.f};

  STAGE(0, 0)
  asm volatile("s_waitcnt vmcnt(0)" ::: "memory");
  __syncthreads();

  int cur = 0;
  for (int k0 = 0; k0 < K; k0 += BK) {
    const bool pfn = (k0 + BK < K);
    if (pfn) { STAGE(cur ^ 1, k0 + BK) }

    s16x8 af[KR][4], bf[KR][NR];
#pragma unroll
    for (int k2 = 0; k2 < KR; ++k2) {
#pragma unroll
      for (int m = 0; m < 4; ++m)
        af[k2][m] = *(const s16x8*)&As[cur][(wr * 64 + m * 16 + lc) * BK + k2 * 32 + kr];
#pragma unroll
      for (int n = 0; n < NR; ++n)
        bf[k2][n] = *(const s16x8*)&Bs[cur][(wc * (BN / 2) + n * 16 + lc) * BK + k2 * 32 + kr];
    }
#pragma unroll
    for (int k2 = 0; k2 < KR; ++k2)
#pragma unroll
      for (int m = 0; m < 4; ++m)
#pragma unroll
        for (int n = 0; n < NR; ++n)
          acc[m][n] = __builtin_amdgcn_mfma_f32_16x16x32_bf16(af[k2][m], bf[k2][n],
                                                              acc[m][n], 0, 0, 0);

    asm volatile("s_waitcnt vmcnt(0)" ::: "memory");
    __syncthreads();
    cur ^= 1;
  }

  int rbase = row0 + wr * 64, cbase = col0 + wc * (BN / 2);
  int lr4 = (lane >> 4) * 4;
#pragma unroll
  for (int m = 0; m < 4; ++m)
#pragma unroll
    for (int n = 0; n < NR; ++n)
#pragma unroll
      for (int r = 0; r < 4; ++r) {
        int grow = rbase + m * 16 + lr4 + r;
        int gcol = cbase + n * 16 + lc;
        float v = acc[m][n][r];
        if (mode == 0) {
          ((unsigned short*)C)[(size_t)grow * ldc + gcol] = f2bf(v);
        } else if (mode == 1) {
          ((float*)C)[(size_t)grow * ldc + gcol] = v + bias[gcol];
        } else {
          int b_ = grow >> 11, t_ = grow & 2047;
          ((unsigned short*)C)[(((size_t)(b_ * 16 + bz)) * 2048 + t_) * 256 + gcol] = f2bf(v);
        }
      }
#undef STAGE
}

// ---------------- flash attention: R13-exact (paired tiles, 2 blocks/CU, LDS V, setprio) ----------------
__global__ __launch_bounds__(256, 2) void k_attn(
    const unsigned short* __restrict__ Qabs, const unsigned short* __restrict__ Lat,
    const unsigned short* __restrict__ VupT, unsigned short* __restrict__ ctx) {
  __shared__ unsigned short Ks[2][32 * 264];
  __shared__ unsigned short Vs[2][64 * 40];
  __shared__ unsigned short Pl[4][16 * 40];

  const int bx = blockIdx.x;
  const int bh = blockIdx.y;
  const int b = bh >> 4, h = bh & 15;
  const int t = threadIdx.x, lane = t & 63, w = t >> 6;
  const int lrow = lane & 15, hi = lane >> 4;
  const int kr = hi * 8;

  const unsigned short* Q = Qabs + (size_t)bh * 2048 * 256;
  const unsigned short* Kp = Lat + (size_t)b * 2048 * 768 + 256;
  const unsigned short* Vp = VupT + (size_t)(h * 64) * 4096 + b * 2048;
  unsigned short* Op = ctx + (size_t)b * 2048 * 1024 + h * 64;

  uint4 kstg[4];
  uint4 vstg;
  const int krr0 = t >> 5;
  const int kcc = t & 31;
  const int vrr = t >> 2, vcc = t & 3;

#define K_ISSUE(s0g)                                                           \
  {                                                                            \
    _Pragma("unroll") for (int c = 0; c < 4; ++c) kstg[c] =                    \
        *(const uint4*)(Kp + (size_t)((s0g) + c * 8 + krr0) * 768 + kcc * 8);  \
    vstg = *(const uint4*)(Vp + (size_t)vrr * 4096 + (s0g) + vcc * 8);         \
  }
#define KV_WRITE(bufi)                                                         \
  {                                                                            \
    _Pragma("unroll") for (int c = 0; c < 4; ++c)                              \
        *(uint4*)&Ks[bufi][(c * 8 + krr0) * 264 + kcc * 8] = kstg[c];          \
    *(uint4*)&Vs[bufi][vrr * 40 + vcc * 8] = vstg;                             \
  }

  for (int seg = 0; seg < 2; ++seg) {
    const int tb = (seg == 0 ? bx : 31 - bx) * 64;
    const int qb = tb + w * 16;

    s16x8 qf[8];
#pragma unroll
    for (int kk = 0; kk < 8; ++kk)
      qf[kk] = *(const s16x8*)&Q[(size_t)(qb + lrow) * 256 + kk * 32 + kr];

    f32x4 o[4];
#pragma unroll
    for (int dt = 0; dt < 4; ++dt) o[dt] = (f32x4){0.f, 0.f, 0.f, 0.f};
    float mrow[4], lsum[4];
    int myrow[4];
#pragma unroll
    for (int r = 0; r < 4; ++r) {
      mrow[r] = -1e30f;
      lsum[r] = 0.f;
      myrow[r] = qb + hi * 4 + r;
    }

    K_ISSUE(0)
    KV_WRITE(0)
    __syncthreads();

    const int nsteps = tb / 32 + 2;
    for (int st = 0; st < nsteps; ++st) {
      const int buf = st & 1;
      const int s0 = st * 32;
      const bool pfn = (st + 1 < nsteps);
      if (pfn) { K_ISSUE(s0 + 32) }

      s16x8 kfa[2][8];
#pragma unroll
      for (int hf = 0; hf < 2; ++hf)
#pragma unroll
        for (int kk = 0; kk < 8; ++kk)
          kfa[hf][kk] = *(const s16x8*)&Ks[buf][(hf * 16 + lrow) * 264 + kk * 32 + kr];

      f32x4 sf[2];
      sf[0] = (f32x4){0.f, 0.f, 0.f, 0.f};
      sf[1] = (f32x4){0.f, 0.f, 0.f, 0.f};
      __builtin_amdgcn_s_setprio(1);
#pragma unroll
      for (int kk = 0; kk < 8; ++kk) {
        sf[0] = __builtin_amdgcn_mfma_f32_16x16x32_bf16(qf[kk], kfa[0][kk], sf[0], 0, 0, 0);
        sf[1] = __builtin_amdgcn_mfma_f32_16x16x32_bf16(qf[kk], kfa[1][kk], sf[1], 0, 0, 0);
      }
      __builtin_amdgcn_s_setprio(0);

#pragma unroll
      for (int r = 0; r < 4; ++r) {
        int q = myrow[r];
        if (s0 + lrow > q) sf[0][r] = -1e30f;
        if (s0 + 16 + lrow > q) sf[1][r] = -1e30f;
        float mloc = fmaxf(sf[0][r], sf[1][r]);
        if (!__all(mloc <= mrow[r] + 8.f)) {
          float mx = mloc;
#pragma unroll
          for (int off = 1; off < 16; off <<= 1) mx = fmaxf(mx, __shfl_xor(mx, off));
          float mnew = fmaxf(mrow[r], mx);
          float scale = __expf(mrow[r] - mnew);
          mrow[r] = mnew;
          lsum[r] *= scale;
#pragma unroll
          for (int dt = 0; dt < 4; ++dt) o[dt][r] *= scale;
        }
        float p0 = __expf(sf[0][r] - mrow[r]);
        float p1 = __expf(sf[1][r] - mrow[r]);
        sf[0][r] = p0;
        sf[1][r] = p1;
        lsum[r] += p0 + p1;
      }
#pragma unroll
      for (int r = 0; r < 4; ++r) {
        Pl[w][(hi * 4 + r) * 40 + lrow] = f2bf(sf[0][r]);
        Pl[w][(hi * 4 + r) * 40 + 16 + lrow] = f2bf(sf[1][r]);
      }
      asm volatile("s_waitcnt lgkmcnt(0)" ::: "memory");
      __builtin_amdgcn_sched_barrier(0);

      s16x8 pf = *(const s16x8*)&Pl[w][lrow * 40 + kr];
      s16x8 vfa[4];
#pragma unroll
      for (int dt = 0; dt < 4; ++dt)
        vfa[dt] = *(const s16x8*)&Vs[buf][(dt * 16 + lrow) * 40 + kr];
      __builtin_amdgcn_s_setprio(1);
#pragma unroll
      for (int dt = 0; dt < 4; ++dt)
        o[dt] = __builtin_amdgcn_mfma_f32_16x16x32_bf16(pf, vfa[dt], o[dt], 0, 0, 0);
      __builtin_amdgcn_s_setprio(0);

      if (pfn) { KV_WRITE(buf ^ 1) }
      __syncthreads();
    }

#pragma unroll
    for (int r = 0; r < 4; ++r) {
      float ls = lsum[r];
#pragma unroll
      for (int off = 1; off < 16; off <<= 1) ls += __shfl_xor(ls, off);
      lsum[r] = ls;
    }
#pragma unroll
    for (int dt = 0; dt < 4; ++dt)
#pragma unroll
      for (int r = 0; r < 4; ++r) {
        float v = o[dt][r] / lsum[r];
        Op[(size_t)myrow[r] * 1024 + dt * 16 + lrow] = f2bf(v);
      }
    __syncthreads();
  }
#undef K_ISSUE
#undef KV_WRITE
}

extern "C" void kernel_launch(void* const* d_in, const int* in_sizes, int n_in,
                              void* d_out, int out_size, void* d_ws, size_t ws_size,
                              hipStream_t stream) {
  const float* x = (const float*)d_in[0];
  const float* Wqd = (const float*)d_in[2];
  const float* Wkd = (const float*)d_in[3];
  const float* Wvd = (const float*)d_in[4];
  const float* Wqu = (const float*)d_in[5];
  const float* Wku = (const float*)d_in[6];
  const float* Wvu = (const float*)d_in[7];
  const float* Wo = (const float*)d_in[8];
  const float* bo = (const float*)d_in[9];
  float* out = (float*)d_out;

  char* ws = (char*)d_ws;
  unsigned short* xb = (unsigned short*)(ws);                // 4096x1024 bf16
  unsigned short* Wdb = (unsigned short*)(ws + 8388608);     // 768x1024
  unsigned short* Wvub = (unsigned short*)(ws + 9961472);    // 1024x256
  unsigned short* Wob = (unsigned short*)(ws + 10485760);    // 1024x1024
  unsigned short* MabsT = (unsigned short*)(ws + 12582912);  // 16x256x256
  unsigned short* Lat = (unsigned short*)(ws + 14680064);    // 4096x768 (Q|K|V latents)
  unsigned short* Qabs = (unsigned short*)(ws + 20971520);   // 32x2048x256
  unsigned short* VupT = (unsigned short*)(ws + 54525952);   // [1024][4096] d-major
  unsigned short* ctx = (unsigned short*)(ws + 62914560);    // 4096x1024

  k_cvt_all<<<6144, 256, 0, stream>>>(x, Wqd, Wkd, Wvd, Wvu, Wo, xb, Wdb, Wvub, Wob);
  k_mabs<<<dim3(4, 4, 16), 256, 0, stream>>>(Wqu, Wku, MabsT);
  // latents: [4096,768] = xb @ Wdb^T   (BN=64, BK=32 — R15-proven best)
  k_gemm<64, 32><<<dim3(32, 12, 1), 256, 0, stream>>>(xb, 1024, Wdb, 1024, 0, Lat, nullptr,
                                                      4096, 768, 1024, 768, 0);
  // Qabs per head (mode 2 scatter): proven BN=128, BK=32 config
  k_gemm<128, 32><<<dim3(32, 2, 16), 256, 0, stream>>>(Lat, 768, MabsT, 256, 65536, Qabs,
                                                       nullptr, 4096, 256, 256, 0, 2);
  // VupT [1024][4096] = Wvub @ V_lat^T  (BN=64, BK=32)
  k_gemm<64, 32><<<dim3(8, 64, 1), 256, 0, stream>>>(Wvub, 256, Lat + 512, 768, 0, VupT,
                                                     nullptr, 1024, 4096, 256, 4096, 0);
  k_attn<<<dim3(16, 32), 256, 0, stream>>>(Qabs, Lat, VupT, ctx);
  // out = ctx @ Wo^T + bo (fp32, BN=64, BK=32)
  k_gemm<64, 32><<<dim3(32, 16, 1), 256, 0, stream>>>(ctx, 1024, Wob, 1024, 0, out, bo,
                                                      4096, 1024, 1024, 1024, 1);
}

// Round 18
// 258.017 us; speedup vs baseline: 1.0112x; 1.0027x over previous
//
#include <hip/hip_runtime.h>

using f32x4 = __attribute__((ext_vector_type(4))) float;
using s16x8 = __attribute__((ext_vector_type(8))) short;
using u16x4 = __attribute__((ext_vector_type(4))) unsigned short;
using u32 = unsigned int;

static __device__ __forceinline__ unsigned short f2bf(float f) {
  u32 u = __builtin_bit_cast(u32, f);
  u = (u + 0x7fffu + ((u >> 16) & 1u)) >> 16;
  return (unsigned short)u;
}

static __device__ __forceinline__ void gload_lds16(const void* g, void* l) {
  __builtin_amdgcn_global_load_lds((const __attribute__((address_space(1))) void*)g,
                                   (__attribute__((address_space(3))) void*)l, 16, 0, 0);
}

// ---------------- fused fp32 -> bf16 conversion (all 6 tensors, one launch) ----------------
__global__ void k_cvt_all(const float* __restrict__ x, const float* __restrict__ Wqd,
                          const float* __restrict__ Wkd, const float* __restrict__ Wvd,
                          const float* __restrict__ Wvu, const float* __restrict__ Wo,
                          unsigned short* __restrict__ xb, unsigned short* __restrict__ Wdb,
                          unsigned short* __restrict__ Wvub, unsigned short* __restrict__ Wob) {
  int i = blockIdx.x * blockDim.x + threadIdx.x;  // float4 index, total 1572864
  const float* s;
  unsigned short* d;
  int off;
  if (i < 1048576) { s = x; d = xb; off = i; }
  else if (i < 1114112) { s = Wqd; d = Wdb; off = i - 1048576; }
  else if (i < 1179648) { s = Wkd; d = Wdb + 262144; off = i - 1114112; }
  else if (i < 1245184) { s = Wvd; d = Wdb + 524288; off = i - 1179648; }
  else if (i < 1310720) { s = Wvu; d = Wvub; off = i - 1245184; }
  else { s = Wo; d = Wob; off = i - 1310720; }
  float4 v = reinterpret_cast<const float4*>(s)[off];
  u16x4 o;
  o[0] = f2bf(v.x); o[1] = f2bf(v.y); o[2] = f2bf(v.z); o[3] = f2bf(v.w);
  reinterpret_cast<u16x4*>(d)[off] = o;
}

// ---------------- MabsT[h][k][q] = 0.125 * sum_d Wq_up[h*64+d][q] * Wk_up[h*64+d][k] ----------------
__global__ void k_mabs(const float* __restrict__ Wqu, const float* __restrict__ Wku,
                       unsigned short* __restrict__ MabsT) {
  __shared__ float sq[64][65];
  __shared__ float sk[64][65];
  int h = blockIdx.z, q0 = blockIdx.x * 64, k0 = blockIdx.y * 64;
  int t = threadIdx.x;
  for (int r = 0; r < 16; ++r) {
    int d = r * 4 + (t >> 6);
    int c = t & 63;
    sq[d][c] = Wqu[(size_t)(h * 64 + d) * 256 + q0 + c];
    sk[d][c] = Wku[(size_t)(h * 64 + d) * 256 + k0 + c];
  }
  __syncthreads();
  int kk = t >> 2, qs = t & 3;
  float acc[16];
#pragma unroll
  for (int j = 0; j < 16; ++j) acc[j] = 0.f;
  for (int d = 0; d < 64; ++d) {
    float kv = sk[d][kk];
#pragma unroll
    for (int j = 0; j < 16; ++j) acc[j] += kv * sq[d][qs + 4 * j];
  }
#pragma unroll
  for (int j = 0; j < 16; ++j)
    MabsT[((size_t)(h * 256 + k0 + kk)) * 256 + q0 + qs + 4 * j] = f2bf(acc[j] * 0.125f);
}

// ---------------- NT-GEMM, gload_lds double-buffered, templated on BN,BK ----------------
// BM=128 fixed. 4 waves: wr=w>>1 over 64 rows, wc=w&1 over BN/2 cols.
// modes: 0 = bf16 C row-major; 1 = fp32 C row-major + bias; 2 = bf16 Qabs scatter
template <int BN, int BK>
__global__ __launch_bounds__(256) void k_gemm(
    const unsigned short* __restrict__ A, int lda,
    const unsigned short* __restrict__ B0, int ldb, long bstride,
    void* __restrict__ C, const float* __restrict__ bias,
    int M, int N, int K, int ldc, int mode) {
  constexpr int NR = BN / 32;       // fragments per wave in N
  constexpr int KR = BK / 32;       // k-subtiles per LDS tile
  constexpr int RA = BK / 16;       // A staging rounds (128*BK*2 / 4096)
  constexpr int RB = BN * BK / 2048;  // B staging rounds
  __shared__ unsigned short As[2][128 * BK];
  __shared__ unsigned short Bs[2][BN * BK];
  int bz = blockIdx.z;
  const unsigned short* B = B0 + (size_t)bz * bstride;
  int row0 = blockIdx.x * 128, col0 = blockIdx.y * BN;
  int t = threadIdx.x;
  int lane = t & 63, w = t >> 6;
  int wr = w >> 1, wc = w & 1;
  int lc = lane & 15, kr = (lane >> 4) * 8;

#define STAGE(bufi, k0g)                                                                   \
  {                                                                                        \
    _Pragma("unroll") for (int c = 0; c < RA; ++c) {                                       \
      int f = (c * 256 + t) * 16;                                                          \
      int r = f / (2 * BK), kb = (f % (2 * BK)) >> 1;                                      \
      gload_lds16(A + (size_t)(row0 + r) * lda + (k0g) + kb,                               \
                  (char*)&As[bufi][0] + c * 4096 + w * 1024);                              \
    }                                                                                      \
    _Pragma("unroll") for (int c = 0; c < RB; ++c) {                                       \
      int f = (c * 256 + t) * 16;                                                          \
      int r = f / (2 * BK), kb = (f % (2 * BK)) >> 1;                                      \
      gload_lds16(B + (size_t)(col0 + r) * ldb + (k0g) + kb,                               \
                  (char*)&Bs[bufi][0] + c * 4096 + w * 1024);                              \
    }                                                                                      \
  }

  f32x4 acc[4][NR];
#pragma unroll
  for (int m = 0; m < 4; ++m)
#pragma unroll
    for (int n = 0; n < NR; ++n) acc[m][n] = (f32x4){0.f, 0.f, 0.f, 0.f};

  STAGE(0, 0)
  asm volatile("s_waitcnt vmcnt(0)" ::: "memory");
  __syncthreads();

  int cur = 0;
  for (int k0 = 0; k0 < K; k0 += BK) {
    const bool pfn = (k0 + BK < K);
    if (pfn) { STAGE(cur ^ 1, k0 + BK) }

    s16x8 af[KR][4], bf[KR][NR];
#pragma unroll
    for (int k2 = 0; k2 < KR; ++k2) {
#pragma unroll
      for (int m = 0; m < 4; ++m)
        af[k2][m] = *(const s16x8*)&As[cur][(wr * 64 + m * 16 + lc) * BK + k2 * 32 + kr];
#pragma unroll
      for (int n = 0; n < NR; ++n)
        bf[k2][n] = *(const s16x8*)&Bs[cur][(wc * (BN / 2) + n * 16 + lc) * BK + k2 * 32 + kr];
    }
#pragma unroll
    for (int k2 = 0; k2 < KR; ++k2)
#pragma unroll
      for (int m = 0; m < 4; ++m)
#pragma unroll
        for (int n = 0; n < NR; ++n)
          acc[m][n] = __builtin_amdgcn_mfma_f32_16x16x32_bf16(af[k2][m], bf[k2][n],
                                                              acc[m][n], 0, 0, 0);

    asm volatile("s_waitcnt vmcnt(0)" ::: "memory");
    __syncthreads();
    cur ^= 1;
  }

  int rbase = row0 + wr * 64, cbase = col0 + wc * (BN / 2);
  int lr4 = (lane >> 4) * 4;
#pragma unroll
  for (int m = 0; m < 4; ++m)
#pragma unroll
    for (int n = 0; n < NR; ++n)
#pragma unroll
      for (int r = 0; r < 4; ++r) {
        int grow = rbase + m * 16 + lr4 + r;
        int gcol = cbase + n * 16 + lc;
        float v = acc[m][n][r];
        if (mode == 0) {
          ((unsigned short*)C)[(size_t)grow * ldc + gcol] = f2bf(v);
        } else if (mode == 1) {
          ((float*)C)[(size_t)grow * ldc + gcol] = v + bias[gcol];
        } else {
          int b_ = grow >> 11, t_ = grow & 2047;
          ((unsigned short*)C)[(((size_t)(b_ * 16 + bz)) * 2048 + t_) * 256 + gcol] = f2bf(v);
        }
      }
#undef STAGE
}

// ---------------- flash attention: R13-exact (paired tiles, 2 blocks/CU, LDS V, setprio) ----------------
__global__ __launch_bounds__(256, 2) void k_attn(
    const unsigned short* __restrict__ Qabs, const unsigned short* __restrict__ Lat,
    const unsigned short* __restrict__ VupT, unsigned short* __restrict__ ctx) {
  __shared__ unsigned short Ks[2][32 * 264];
  __shared__ unsigned short Vs[2][64 * 40];
  __shared__ unsigned short Pl[4][16 * 40];

  const int bx = blockIdx.x;
  const int bh = blockIdx.y;
  const int b = bh >> 4, h = bh & 15;
  const int t = threadIdx.x, lane = t & 63, w = t >> 6;
  const int lrow = lane & 15, hi = lane >> 4;
  const int kr = hi * 8;

  const unsigned short* Q = Qabs + (size_t)bh * 2048 * 256;
  const unsigned short* Kp = Lat + (size_t)b * 2048 * 768 + 256;
  const unsigned short* Vp = VupT + (size_t)(h * 64) * 4096 + b * 2048;
  unsigned short* Op = ctx + (size_t)b * 2048 * 1024 + h * 64;

  uint4 kstg[4];
  uint4 vstg;
  const int krr0 = t >> 5;
  const int kcc = t & 31;
  const int vrr = t >> 2, vcc = t & 3;

#define K_ISSUE(s0g)                                                           \
  {                                                                            \
    _Pragma("unroll") for (int c = 0; c < 4; ++c) kstg[c] =                    \
        *(const uint4*)(Kp + (size_t)((s0g) + c * 8 + krr0) * 768 + kcc * 8);  \
    vstg = *(const uint4*)(Vp + (size_t)vrr * 4096 + (s0g) + vcc * 8);         \
  }
#define KV_WRITE(bufi)                                                         \
  {                                                                            \
    _Pragma("unroll") for (int c = 0; c < 4; ++c)                              \
        *(uint4*)&Ks[bufi][(c * 8 + krr0) * 264 + kcc * 8] = kstg[c];          \
    *(uint4*)&Vs[bufi][vrr * 40 + vcc * 8] = vstg;                             \
  }

  for (int seg = 0; seg < 2; ++seg) {
    const int tb = (seg == 0 ? bx : 31 - bx) * 64;
    const int qb = tb + w * 16;

    s16x8 qf[8];
#pragma unroll
    for (int kk = 0; kk < 8; ++kk)
      qf[kk] = *(const s16x8*)&Q[(size_t)(qb + lrow) * 256 + kk * 32 + kr];

    f32x4 o[4];
#pragma unroll
    for (int dt = 0; dt < 4; ++dt) o[dt] = (f32x4){0.f, 0.f, 0.f, 0.f};
    float mrow[4], lsum[4];
    int myrow[4];
#pragma unroll
    for (int r = 0; r < 4; ++r) {
      mrow[r] = -1e30f;
      lsum[r] = 0.f;
      myrow[r] = qb + hi * 4 + r;
    }

    K_ISSUE(0)
    KV_WRITE(0)
    __syncthreads();

    const int nsteps = tb / 32 + 2;
    for (int st = 0; st < nsteps; ++st) {
      const int buf = st & 1;
      const int s0 = st * 32;
      const bool pfn = (st + 1 < nsteps);
      if (pfn) { K_ISSUE(s0 + 32) }

      s16x8 kfa[2][8];
#pragma unroll
      for (int hf = 0; hf < 2; ++hf)
#pragma unroll
        for (int kk = 0; kk < 8; ++kk)
          kfa[hf][kk] = *(const s16x8*)&Ks[buf][(hf * 16 + lrow) * 264 + kk * 32 + kr];

      f32x4 sf[2];
      sf[0] = (f32x4){0.f, 0.f, 0.f, 0.f};
      sf[1] = (f32x4){0.f, 0.f, 0.f, 0.f};
      __builtin_amdgcn_s_setprio(1);
#pragma unroll
      for (int kk = 0; kk < 8; ++kk) {
        sf[0] = __builtin_amdgcn_mfma_f32_16x16x32_bf16(qf[kk], kfa[0][kk], sf[0], 0, 0, 0);
        sf[1] = __builtin_amdgcn_mfma_f32_16x16x32_bf16(qf[kk], kfa[1][kk], sf[1], 0, 0, 0);
      }
      __builtin_amdgcn_s_setprio(0);

#pragma unroll
      for (int r = 0; r < 4; ++r) {
        int q = myrow[r];
        if (s0 + lrow > q) sf[0][r] = -1e30f;
        if (s0 + 16 + lrow > q) sf[1][r] = -1e30f;
        float mloc = fmaxf(sf[0][r], sf[1][r]);
        if (!__all(mloc <= mrow[r] + 8.f)) {
          float mx = mloc;
#pragma unroll
          for (int off = 1; off < 16; off <<= 1) mx = fmaxf(mx, __shfl_xor(mx, off));
          float mnew = fmaxf(mrow[r], mx);
          float scale = __expf(mrow[r] - mnew);
          mrow[r] = mnew;
          lsum[r] *= scale;
#pragma unroll
          for (int dt = 0; dt < 4; ++dt) o[dt][r] *= scale;
        }
        float p0 = __expf(sf[0][r] - mrow[r]);
        float p1 = __expf(sf[1][r] - mrow[r]);
        sf[0][r] = p0;
        sf[1][r] = p1;
        lsum[r] += p0 + p1;
      }
#pragma unroll
      for (int r = 0; r < 4; ++r) {
        Pl[w][(hi * 4 + r) * 40 + lrow] = f2bf(sf[0][r]);
        Pl[w][(hi * 4 + r) * 40 + 16 + lrow] = f2bf(sf[1][r]);
      }
      asm volatile("s_waitcnt lgkmcnt(0)" ::: "memory");
      __builtin_amdgcn_sched_barrier(0);

      s16x8 pf = *(const s16x8*)&Pl[w][lrow * 40 + kr];
      s16x8 vfa[4];
#pragma unroll
      for (int dt = 0; dt < 4; ++dt)
        vfa[dt] = *(const s16x8*)&Vs[buf][(dt * 16 + lrow) * 40 + kr];
      __builtin_amdgcn_s_setprio(1);
#pragma unroll
      for (int dt = 0; dt < 4; ++dt)
        o[dt] = __builtin_amdgcn_mfma_f32_16x16x32_bf16(pf, vfa[dt], o[dt], 0, 0, 0);
      __builtin_amdgcn_s_setprio(0);

      if (pfn) { KV_WRITE(buf ^ 1) }
      __syncthreads();
    }

#pragma unroll
    for (int r = 0; r < 4; ++r) {
      float ls = lsum[r];
#pragma unroll
      for (int off = 1; off < 16; off <<= 1) ls += __shfl_xor(ls, off);
      lsum[r] = ls;
    }
#pragma unroll
    for (int dt = 0; dt < 4; ++dt)
#pragma unroll
      for (int r = 0; r < 4; ++r) {
        float v = o[dt][r] / lsum[r];
        Op[(size_t)myrow[r] * 1024 + dt * 16 + lrow] = f2bf(v);
      }
    __syncthreads();
  }
#undef K_ISSUE
#undef KV_WRITE
}

extern "C" void kernel_launch(void* const* d_in, const int* in_sizes, int n_in,
                              void* d_out, int out_size, void* d_ws, size_t ws_size,
                              hipStream_t stream) {
  const float* x = (const float*)d_in[0];
  const float* Wqd = (const float*)d_in[2];
  const float* Wkd = (const float*)d_in[3];
  const float* Wvd = (const float*)d_in[4];
  const float* Wqu = (const float*)d_in[5];
  const float* Wku = (const float*)d_in[6];
  const float* Wvu = (const float*)d_in[7];
  const float* Wo = (const float*)d_in[8];
  const float* bo = (const float*)d_in[9];
  float* out = (float*)d_out;

  char* ws = (char*)d_ws;
  unsigned short* xb = (unsigned short*)(ws);                // 4096x1024 bf16
  unsigned short* Wdb = (unsigned short*)(ws + 8388608);     // 768x1024
  unsigned short* Wvub = (unsigned short*)(ws + 9961472);    // 1024x256
  unsigned short* Wob = (unsigned short*)(ws + 10485760);    // 1024x1024
  unsigned short* MabsT = (unsigned short*)(ws + 12582912);  // 16x256x256
  unsigned short* Lat = (unsigned short*)(ws + 14680064);    // 4096x768 (Q|K|V latents)
  unsigned short* Qabs = (unsigned short*)(ws + 20971520);   // 32x2048x256
  unsigned short* VupT = (unsigned short*)(ws + 54525952);   // [1024][4096] d-major
  unsigned short* ctx = (unsigned short*)(ws + 62914560);    // 4096x1024

  k_cvt_all<<<6144, 256, 0, stream>>>(x, Wqd, Wkd, Wvd, Wvu, Wo, xb, Wdb, Wvub, Wob);
  k_mabs<<<dim3(4, 4, 16), 256, 0, stream>>>(Wqu, Wku, MabsT);
  // latents: [4096,768] = xb @ Wdb^T   (BN=64, BK=32 — proven best)
  k_gemm<64, 32><<<dim3(32, 12, 1), 256, 0, stream>>>(xb, 1024, Wdb, 1024, 0, Lat, nullptr,
                                                      4096, 768, 1024, 768, 0);
  // Qabs per head (mode 2 scatter): proven BN=128, BK=32 config
  k_gemm<128, 32><<<dim3(32, 2, 16), 256, 0, stream>>>(Lat, 768, MabsT, 256, 65536, Qabs,
                                                       nullptr, 4096, 256, 256, 0, 2);
  // VupT [1024][4096] = Wvub @ V_lat^T  (BN=64, BK=32)
  k_gemm<64, 32><<<dim3(8, 64, 1), 256, 0, stream>>>(Wvub, 256, Lat + 512, 768, 0, VupT,
                                                     nullptr, 1024, 4096, 256, 4096, 0);
  k_attn<<<dim3(16, 32), 256, 0, stream>>>(Qabs, Lat, VupT, ctx);
  // out = ctx @ Wo^T + bo (fp32, BN=64, BK=32)
  k_gemm<64, 32><<<dim3(32, 16, 1), 256, 0, stream>>>(ctx, 1024, Wob, 1024, 0, out, bo,
                                                      4096, 1024, 1024, 1024, 1);
}